// Round 17
// baseline (101.296 us; speedup 1.0000x reference)
//
#include <hip/hip_runtime.h>

typedef __bf16 bf16x8 __attribute__((ext_vector_type(8)));
typedef float f32x16 __attribute__((ext_vector_type(16)));
typedef unsigned short u16x8 __attribute__((ext_vector_type(8)));

constexpr int B = 4, S = 4096, D = 256;
// log2(e) / sqrt(D) = 1.4426950408889634 / 16
constexpr float CSC = 0.09016844005556021f;

static __device__ __forceinline__ unsigned short f2bf(float f) {
  unsigned int u = __builtin_bit_cast(unsigned int, f);
  u = (u + 0x7fffu + ((u >> 16) & 1u)) >> 16;
  return (unsigned short)u;
}

static __device__ __forceinline__ float bf2f(unsigned short u) {
  unsigned int v = ((unsigned int)u) << 16;
  return __builtin_bit_cast(float, v);
}

// pack two f32 -> 2x bf16 (RNE), low half = lo
static __device__ __forceinline__ unsigned int pk2bf(float lo, float hi) {
  unsigned int r;
  asm("v_cvt_pk_bf16_f32 %0, %1, %2" : "=v"(r) : "v"(lo), "v"(hi));
  return r;
}

// async global->LDS, 16B per lane; LDS dest = wave-uniform base + lane*16
static __device__ __forceinline__ void gld16(const void* g, void* l) {
  __builtin_amdgcn_global_load_lds(
      (const __attribute__((address_space(1))) unsigned int*)g,
      (__attribute__((address_space(3))) unsigned int*)l, 16, 0, 0);
}

#define FENCE_V4()                                                \
  do {                                                            \
    asm volatile("s_waitcnt vmcnt(4) lgkmcnt(0)" ::: "memory");   \
    __builtin_amdgcn_s_barrier();                                 \
    asm volatile("" ::: "memory");                                \
  } while (0)
#define FENCE_V8()                                                \
  do {                                                            \
    asm volatile("s_waitcnt vmcnt(8) lgkmcnt(0)" ::: "memory");   \
    __builtin_amdgcn_s_barrier();                                 \
    asm volatile("" ::: "memory");                                \
  } while (0)
#define FENCE_ALL0()                                              \
  do {                                                            \
    asm volatile("s_waitcnt vmcnt(0) lgkmcnt(0)" ::: "memory");   \
    __builtin_amdgcn_s_barrier();                                 \
    asm volatile("" ::: "memory");                                \
  } while (0)

// ---- kernel 1: cast x -> bf16 into hi-interleaved subtiled xK, xV ----
// xK[b][tile(64kv)][s(16)][hi(2)][row(64)][8elts]: elt = X[kv=t*64+row][k=s*16+hi*8+e]
// xV[b][tile(64kv)][c(4)][hi(2)][d(256)][8elts]:  elt = X[kv=t*64+c*16+hi*8+e][d]
__global__ __launch_bounds__(256) void k_prep(const float* __restrict__ x,
                                              unsigned short* __restrict__ xK,
                                              unsigned short* __restrict__ xV) {
  __shared__ unsigned short T[64][72];  // T[d_local][s_local]
  __shared__ unsigned short R[64][72];  // R[s_local][d_local]
  int bid = blockIdx.x;
  int b = bid >> 8, rem = bid & 255;
  int s0 = (rem >> 2) * 64, d0 = (rem & 3) * 64;
  int j = threadIdx.x & 63, i0 = threadIdx.x >> 6;
#pragma unroll
  for (int k = 0; k < 16; ++k) {
    int i = k * 4 + i0;
    int idx = (b * S + s0 + i) * D + d0 + j;
    unsigned short v = f2bf(x[idx]);
    T[j][i] = v;
    R[i][j] = v;
  }
  __syncthreads();
  int t = s0 >> 6;
#pragma unroll
  for (int p = 0; p < 2; ++p) {
    int cc = p * 256 + threadIdx.x;
    int sl8 = cc >> 6, row = cc & 63;
    u16x8 v = *(const u16x8*)&R[row][sl8 * 8];
    int dg = d0 + sl8 * 8;
    int s = dg >> 4, hi = (dg >> 3) & 1;
    size_t off = ((((size_t)(b * 64 + t) * 16 + s) * 2 + hi) * 64 + row) * 8;
    *(u16x8*)(xK + off) = v;
  }
#pragma unroll
  for (int p = 0; p < 2; ++p) {
    int cc = p * 256 + threadIdx.x;
    int c = cc >> 7, hi = (cc >> 6) & 1, dl = cc & 63;
    u16x8 v = *(const u16x8*)&T[dl][c * 16 + hi * 8];
    size_t off = ((((size_t)(b * 64 + t) * 4 + c) * 2 + hi) * 256 + (d0 + dl)) * 8;
    *(u16x8*)(xV + off) = v;
  }
}

// ---- kernel 2: w_int -> bf16, subtiled wK[s(16)][hi(2)][o(256)][8elts] ----
__global__ __launch_bounds__(256) void k_deqw(const int* __restrict__ w,
                                              unsigned short* __restrict__ wK) {
  int o = blockIdx.x, d = threadIdx.x;
  unsigned short v = f2bf((float)w[o * 256 + d]);
  wK[(((d >> 4) * 2 + ((d >> 3) & 1)) * 256 + o) * 8 + (d & 7)] = v;
}

// ---- kernel 3: flash attention, single-barrier pipeline, V triple-buffer ----
// 256 blocks = 128 q-groups x 2 kv-halves (32 tiles). 8 waves = 4 pairs.
// Iter t: FENCE[vmcnt(4)+lgkm+bar] -> STAGE_K(t+1) -> STAGE_V(t+1) ->
//   QK(t, kb[t&1]) -> PV(t-1, vb[(t-1)%3]) -> SM(t).
// Hazards: K(t) staged 1 iter ago (vmcnt(4) leaves only V(t) in flight);
// V(t-1) staged 2 iters ago; overwritten buffers' readers drained by the
// barrier's lgkmcnt(0); vb write idx differs from PV read idx by 2 mod 3.
// LDS = K 2x32K + V 3x32K = 160 KiB exactly; LX/epilogue alias after drain.
// m==0 softmax (R10), permlane32_swap (R13), hi-interleaved layouts (R15).
__global__ __launch_bounds__(512, 2) void k_attn(const unsigned short* __restrict__ xK,
                                                 const unsigned short* __restrict__ xV,
                                                 unsigned short* __restrict__ PO0,
                                                 unsigned short* __restrict__ PO1,
                                                 float* __restrict__ ML) {
  __shared__ __align__(16) char smem[163840];
  // kb0 @0, kb1 @32768; vb0 @65536, vb1 @98304, vb2 @131072.
  // post-loop: LX @131072 (1KB, inside vb2 — dead), epilogue slots @0.

  int tid = threadIdx.x;
  int w = tid >> 6, lane = tid & 63;
  int q5 = lane & 31, hi = lane >> 5;
  int pair = w >> 1, dh = w & 1;

  int bid = blockIdx.x;
  int swz = (bid & 7) * 32 + (bid >> 3);  // bijective XCD swizzle (256 % 8 == 0)
  int h = swz & 1;    // kv half
  int qg = swz >> 1;  // q-group 0..127
  int q0 = qg * 128;  // global q row base
  int bat = q0 >> 12;
  int qloc = q0 & (S - 1);

  // Q fragments from xK layout: row qrow, k = s*16 + hi*8 + e
  int qrow = qloc + pair * 32 + q5;
  const unsigned short* Qb =
      xK + (size_t)(bat * 64 + (qrow >> 6)) * 16384 + hi * 512 + (qrow & 63) * 8;
  bf16x8 qf[16];
#pragma unroll
  for (int s = 0; s < 16; ++s) qf[s] = *(const bf16x8*)(Qb + s * 1024);

  f32x16 acc[8];  // O^T partial (own kv-half): acc[dt][r]=O^T[d=dt*32+crow(r,hi)][q5]
#pragma unroll
  for (int dt = 0; dt < 8; ++dt)
#pragma unroll
    for (int j = 0; j < 16; ++j) acc[dt][j] = 0.f;
  float l_lane = 0.f;
  unsigned int paw[8];  // pa words: persist across iterations

  const char* xKb = (const char*)xK + (size_t)(bat * 64 + h * 32) * 32768;
  const char* xVb = (const char*)xV + (size_t)(bat * 64 + h * 32) * 32768;

  auto STAGE_K = [&](int itile, int kb) {
    char* Kd = smem + kb * 32768;
    const char* srcK = xKb + (size_t)itile * 32768;
#pragma unroll
    for (int i = 0; i < 4; ++i) {
      int off = (w * 2 + (i >> 1)) * 2048 + (i & 1) * 1024;
      gld16(srcK + off + lane * 16, Kd + off);
    }
  };
  auto STAGE_V = [&](int itile, int vb) {
    char* Vd = smem + 65536 + vb * 32768;
    const char* srcV = xVb + (size_t)itile * 32768;
#pragma unroll
    for (int i = 0; i < 4; ++i) {
      int off = (w >> 1) * 8192 + ((w & 1) * 4 + i) * 1024;
      gld16(srcV + off + lane * 16, Vd + off);
    }
  };

  // QK(t): st = K[kb]^T x Q  (st[r] = S[kv=dh*32+crow(r,hi)][q=qrow])
  auto QK = [&](int kb, f32x16& st) {
    const char* Kt = smem + kb * 32768 + hi * 1024 + dh * 512 + q5 * 16;
#pragma unroll
    for (int j = 0; j < 16; ++j) st[j] = 0.f;
    __builtin_amdgcn_s_setprio(1);
#pragma unroll
    for (int s = 0; s < 16; ++s) {
      bf16x8 kf = *(const bf16x8*)(Kt + s * 2048);
      st = __builtin_amdgcn_mfma_f32_32x32x16_bf16(kf, qf[s], st, 0, 0, 0);
    }
    __builtin_amdgcn_s_setprio(0);
  };
  // PV: acc += V[vb] x pa(paw)
  auto PV = [&](int vb) {
    union PA { unsigned int u[4]; bf16x8 v; };
    PA pa0, pa1;
    pa0.u[0] = paw[0]; pa0.u[1] = paw[1]; pa0.u[2] = paw[2]; pa0.u[3] = paw[3];
    pa1.u[0] = paw[4]; pa1.u[1] = paw[5]; pa1.u[2] = paw[6]; pa1.u[3] = paw[7];
    __builtin_amdgcn_s_setprio(1);
#pragma unroll
    for (int s2i = 0; s2i < 2; ++s2i) {
      const char* Vt = smem + 65536 + vb * 32768 + (dh * 2 + s2i) * 8192 +
                       hi * 4096 + q5 * 16;
      bf16x8 pa = (s2i == 0) ? pa0.v : pa1.v;
#pragma unroll
      for (int dt = 0; dt < 8; ++dt) {
        bf16x8 vf = *(const bf16x8*)(Vt + dt * 512);
        acc[dt] = __builtin_amdgcn_mfma_f32_32x32x16_bf16(vf, pa, acc[dt], 0, 0, 0);
      }
    }
    __builtin_amdgcn_s_setprio(0);
  };
  // softmax: P = exp2(st*CSC); pack; permlane exchange -> paw
  auto SM = [&](const f32x16& st) {
    unsigned int pk[8];
    float ps = 0.f;
#pragma unroll
    for (int a = 0; a < 8; ++a) {
      float lo = exp2f(st[2 * a] * CSC);
      float hh = exp2f(st[2 * a + 1] * CSC);
      ps += lo + hh;
      pk[a] = pk2bf(lo, hh);
    }
    l_lane += ps;
    unsigned int a0 = pk[0], b0 = pk[2];
    unsigned int a1 = pk[1], b1 = pk[3];
    unsigned int a2 = pk[4], b2 = pk[6];
    unsigned int a3 = pk[5], b3 = pk[7];
    asm volatile("v_permlane32_swap_b32 %0, %1" : "+v"(a0), "+v"(b0));
    asm volatile("v_permlane32_swap_b32 %0, %1" : "+v"(a1), "+v"(b1));
    asm volatile("v_permlane32_swap_b32 %0, %1" : "+v"(a2), "+v"(b2));
    asm volatile("v_permlane32_swap_b32 %0, %1" : "+v"(a3), "+v"(b3));
    paw[0] = a0; paw[1] = a1; paw[2] = b0; paw[3] = b1;
    paw[4] = a2; paw[5] = a3; paw[6] = b2; paw[7] = b3;
  };

  // ---- prologue: stage K0,V0,K1,V1 (16 loads); wait K0,V0; QK(0)+SM(0)
  STAGE_K(0, 0);
  STAGE_V(0, 0);
  STAGE_K(1, 1);
  STAGE_V(1, 1);
  FENCE_V8();  // K0,V0 complete; K1,V1 (8 newest) may fly
  {
    f32x16 st;
    QK(0, st);
    SM(st);  // pa(0)
  }

  // ---- main pipeline: t = 1..31, ONE barrier per tile
  for (int t = 1; t < 32; ++t) {
    FENCE_V4();  // K(t), V(t-1) complete; V(t) (4 newest) may fly
    if (t < 31) {
      STAGE_K(t + 1, (t + 1) & 1);  // overwrites K(t-1); readers drained
      STAGE_V(t + 1, (t + 1) % 3);  // overwrites V(t-2); readers drained
    }
    f32x16 st;
    QK(t & 1, st);      // MFMA: QK(t)
    PV((t - 1) % 3);    // MFMA: PV(t-1) with old paw
    SM(st);             // VALU: pa(t), overlaps PV drain
  }

  // ---- epilogue PV(31): V(31) in vb[31%3=1]
  FENCE_ALL0();
  PV(1);

  // ---- l: own wave (hi halves) + pair partner via LDS (LX @131072, dead vb2)
  float lw = l_lane + __shfl_xor(l_lane, 32, 64);
  float* LX = (float*)(smem + 131072);
  if (lane < 32) LX[w * 32 + q5] = lw;
  __syncthreads();  // also drains all PV(31) LDS reads before slot overwrite
  float l_tot = lw + LX[(w ^ 1) * 32 + q5];
  if (dh == 0 && lane < 32) {
    int row = q0 + pair * 32 + q5;
    ML[((size_t)h * 16384 + row) * 2 + 0] = 0.f;
    ML[((size_t)h * 16384 + row) * 2 + 1] = l_tot;
  }
  __syncthreads();

  // ---- epilogue: 2-round pair merge (f32 via LDS) + transpose + store
  unsigned short* Pb2 = (h == 0) ? PO0 : PO1;
#pragma unroll
  for (int rh = 0; rh < 2; ++rh) {
    float* slot = (float*)(smem + w * 16384);  // [dloc(128)][q(32)] f32
#pragma unroll
    for (int dt4 = 0; dt4 < 4; ++dt4) {
#pragma unroll
      for (int r = 0; r < 16; ++r) {
        int dloc = dt4 * 32 + (r & 3) + 8 * (r >> 2) + 4 * hi;
        slot[dloc * 32 + q5] = acc[rh * 4 + dt4][r];
      }
    }
    __syncthreads();
    if (dh == rh) {
      const float* pslot = (const float*)(smem + (w ^ 1) * 16384);
#pragma unroll
      for (int dt4 = 0; dt4 < 4; ++dt4) {
#pragma unroll
        for (int r = 0; r < 16; ++r) {
          int dloc = dt4 * 32 + (r & 3) + 8 * (r >> 2) + 4 * hi;
          acc[rh * 4 + dt4][r] += pslot[dloc * 32 + q5];
        }
      }
      // transpose through own slot (E), then coalesced global store
      char* E = smem + w * 16384;  // [32 q][272B]
#pragma unroll
      for (int dt4 = 0; dt4 < 4; ++dt4) {
#pragma unroll
        for (int a = 0; a < 4; ++a) {
          int dl = dt4 * 32 + 8 * a + 4 * hi;
          *(unsigned int*)(E + q5 * 272 + dl * 2) =
              pk2bf(acc[rh * 4 + dt4][4 * a + 0], acc[rh * 4 + dt4][4 * a + 1]);
          *(unsigned int*)(E + q5 * 272 + dl * 2 + 4) =
              pk2bf(acc[rh * 4 + dt4][4 * a + 2], acc[rh * 4 + dt4][4 * a + 3]);
        }
      }
      asm volatile("s_waitcnt lgkmcnt(0)" ::: "memory");
#pragma unroll
      for (int i = 0; i < 8; ++i) {
        int qr = i * 4 + (lane >> 4);
        int ch = lane & 15;
        u16x8 v = *(const u16x8*)(E + qr * 272 + ch * 16);
        *(u16x8*)(Pb2 + (size_t)(q0 + pair * 32 + qr) * 256 + rh * 128 + ch * 8) = v;
      }
    }
    __syncthreads();
  }
}

// ---- kernel 4: fused merge + GEMM, W staged once in LDS ----
__global__ __launch_bounds__(512, 2) void k_gemm(const unsigned short* __restrict__ PO0,
                                                 const unsigned short* __restrict__ PO1,
                                                 const float* __restrict__ ML,
                                                 const unsigned short* __restrict__ wK,
                                                 const float* __restrict__ scale,
                                                 float* __restrict__ out) {
  __shared__ __align__(16) char Wl[131072];
  int tid = threadIdx.x;
  int w = tid >> 6, lane = tid & 63;
  int q5 = lane & 31, hi = lane >> 5;
  int msub = w & 1, oq = w >> 1;
  int m0 = blockIdx.x * 64;

#pragma unroll
  for (int i = 0; i < 16; ++i) {
    int off = (i * 512 + tid) * 16;
    gld16((const char*)wK + off, Wl + off);
  }

  int row = m0 + msub * 32 + q5;
  float il = 1.f / (ML[(size_t)row * 2 + 1] + ML[((size_t)16384 + row) * 2 + 1]);

  bf16x8 af[16];
#pragma unroll
  for (int s = 0; s < 16; ++s) {
    u16x8 a0 = *(const u16x8*)(PO0 + (size_t)row * 256 + s * 16 + hi * 8);
    u16x8 a1 = *(const u16x8*)(PO1 + (size_t)row * 256 + s * 16 + hi * 8);
    union { unsigned int u[4]; bf16x8 v; } cv;
#pragma unroll
    for (int e = 0; e < 4; ++e) {
      float lo = (bf2f(a0[2 * e]) + bf2f(a1[2 * e])) * il;
      float hh = (bf2f(a0[2 * e + 1]) + bf2f(a1[2 * e + 1])) * il;
      cv.u[e] = pk2bf(lo, hh);
    }
    af[s] = cv.v;
  }

  asm volatile("s_waitcnt vmcnt(0)" ::: "memory");
  __builtin_amdgcn_s_barrier();

  f32x16 acc[2];
#pragma unroll
  for (int t = 0; t < 2; ++t)
#pragma unroll
    for (int j = 0; j < 16; ++j) acc[t][j] = 0.f;

#pragma unroll
  for (int t = 0; t < 2; ++t) {
    int obase = (oq * 2 + t) * 32;
    const char* Wt = Wl + hi * 4096 + (obase + q5) * 16;
#pragma unroll
    for (int s = 0; s < 16; ++s) {
      bf16x8 wf = *(const bf16x8*)(Wt + s * 8192);
      acc[t] = __builtin_amdgcn_mfma_f32_32x32x16_bf16(af[s], wf, acc[t], 0, 0, 0);
    }
  }

#pragma unroll
  for (int t = 0; t < 2; ++t) {
    int o = (oq * 2 + t) * 32 + q5;
    float sc = scale[o];
#pragma unroll
    for (int r = 0; r < 16; ++r) {
      int mr = m0 + msub * 32 + (r & 3) + 8 * (r >> 2) + 4 * hi;
      out[(size_t)mr * 256 + o] = acc[t][r] * sc;
    }
  }
}

extern "C" void kernel_launch(void* const* d_in, const int* in_sizes, int n_in,
                              void* d_out, int out_size, void* d_ws, size_t ws_size,
                              hipStream_t stream) {
  (void)in_sizes; (void)n_in; (void)out_size; (void)ws_size;
  const float* x = (const float*)d_in[0];
  const int* w_int = (const int*)d_in[1];
  const float* scale = (const float*)d_in[2];
  float* out = (float*)d_out;

  char* ws = (char*)d_ws;
  unsigned short* xK  = (unsigned short*)(ws);               // 8 MB
  unsigned short* xV  = (unsigned short*)(ws + 8388608);     // 8 MB
  unsigned short* wK  = (unsigned short*)(ws + 16777216);    // 128 KB (subtiled)
  float*          ML  = (float*)(ws + 16908288);             // 256 KB
  unsigned short* PO0 = (unsigned short*)(ws + 17170432);    // 8 MB
  unsigned short* PO1 = (unsigned short*)(ws + 25559040);    // 8 MB

  k_prep<<<dim3(1024), dim3(256), 0, stream>>>(x, xK, xV);
  k_deqw<<<dim3(256), dim3(256), 0, stream>>>(w_int, wK);
  k_attn<<<dim3(256), dim3(512), 0, stream>>>(xK, xV, PO0, PO1, ML);
  k_gemm<<<dim3(256), dim3(512), 0, stream>>>(PO0, PO1, ML, wK, scale, out);
}